// Round 4
// baseline (44.145 us; speedup 1.0000x reference)
//
#include <hip/hip_runtime.h>
#include <hip/hip_bf16.h>

#define BATCH 64
#define NADJ  512
#define F     128
#define CROP0 128
#define CROP1 384
#define CN    256
#define BN_EPS 1e-5f

typedef __attribute__((ext_vector_type(8))) short short8;
typedef __attribute__((ext_vector_type(4))) float f32x4;

__device__ __forceinline__ ushort f2bf(float x) {
  __hip_bfloat16 h = __float2bfloat16(x);  // RNE
  return *reinterpret_cast<ushort*>(&h);
}

__device__ __forceinline__ short8 cvt8(const float4 a, const float4 b) {
  short8 r;
  r[0] = (short)f2bf(a.x); r[1] = (short)f2bf(a.y);
  r[2] = (short)f2bf(a.z); r[3] = (short)f2bf(a.w);
  r[4] = (short)f2bf(b.x); r[5] = (short)f2bf(b.y);
  r[6] = (short)f2bf(b.z); r[7] = (short)f2bf(b.w);
  return r;
}

// ---------------------------------------------------------------------------
// W-prep: Wt[f][i] = bf16(W[i][f]).  128 blocks x 128 threads.
// Reads strided (L2-absorbed, W=64KB), writes coalesced 256B/block.
// ---------------------------------------------------------------------------
__global__ __launch_bounds__(128) void wprep(const float* __restrict__ W,
                                             ushort* __restrict__ Wt) {
  const int f = blockIdx.x;
  const int i = threadIdx.x;
  Wt[(size_t)f * F + i] = f2bf(W[(size_t)i * F + f]);
}

// ---------------------------------------------------------------------------
// K1: St[b][f][m] = bf16( (input_crop @ W)^T ).  No LDS, no barriers.
// 2048 waves: wave tile 16m x 64f, K=128. A-frags from global fp32 input
// (converted in-reg), B-frags from L1/L2-resident Wt bf16.
// ---------------------------------------------------------------------------
__global__ __launch_bounds__(256) void support_k(
    const float* __restrict__ input, const ushort* __restrict__ Wt,
    ushort* __restrict__ St) {
  const int gw = blockIdx.x * 4 + (threadIdx.x >> 6);  // 0..2047
  const int l  = threadIdx.x & 63;
  const int lr = l & 15, lg = l >> 4;
  const int mt = gw >> 1;             // 1024 m-tiles of 16 rows
  const int f0 = (gw & 1) * 64;
  const int b  = mt >> 4;             // 16 m-tiles per batch
  const int m0 = (mt & 15) * 16;      // within crop

  const float* arow = input + ((size_t)b * NADJ + CROP0 + m0 + lr) * F;
  f32x4 acc[4] = {};
#pragma unroll
  for (int ks = 0; ks < 4; ++ks) {
    const int k0 = ks * 32 + lg * 8;
    const float4 x0 = *reinterpret_cast<const float4*>(&arow[k0]);
    const float4 x1 = *reinterpret_cast<const float4*>(&arow[k0 + 4]);
    const short8 av = cvt8(x0, x1);
#pragma unroll
    for (int fi = 0; fi < 4; ++fi) {
      const short8 bv = *reinterpret_cast<const short8*>(
          &Wt[(size_t)(f0 + fi * 16 + lr) * F + k0]);
      acc[fi] =
          __builtin_amdgcn_mfma_f32_16x16x32_bf16(av, bv, acc[fi], 0, 0, 0);
    }
  }
  // D: col(f)=lane&15, row(m)=4*(lane>>4)+reg -> 4 consecutive m per lane
#pragma unroll
  for (int fi = 0; fi < 4; ++fi) {
    const int f = f0 + fi * 16 + lr;
    *reinterpret_cast<ushort4*>(&St[((size_t)b * F + f) * CN + m0 + lg * 4]) =
        make_ushort4(f2bf(acc[fi][0]), f2bf(acc[fi][1]), f2bf(acc[fi][2]),
                     f2bf(acc[fi][3]));
  }
}

// ---------------------------------------------------------------------------
// K2: out_crop[b][n][f] = adj_crop[b][n][:] @ S[b][:][f].  No LDS/barriers.
// 2048 waves: wave tile 16n x 64f, K=256. A-frags from global fp32 adj,
// B-frags from L2-resident St bf16.
// ---------------------------------------------------------------------------
__global__ __launch_bounds__(256) void aggregate_k(
    const float* __restrict__ adj, const ushort* __restrict__ St,
    float* __restrict__ out) {
  const int gw = blockIdx.x * 4 + (threadIdx.x >> 6);
  const int l  = threadIdx.x & 63;
  const int lr = l & 15, lg = l >> 4;
  const int nt = gw >> 1;
  const int f0 = (gw & 1) * 64;
  const int b  = nt >> 4;
  const int n0 = (nt & 15) * 16;

  const float* arow =
      adj + ((size_t)b * NADJ + CROP0 + n0 + lr) * NADJ + CROP0;
  const ushort* Stb = St + (size_t)b * F * CN;
  f32x4 acc[4] = {};
#pragma unroll 4
  for (int ks = 0; ks < 8; ++ks) {
    const int k0 = ks * 32 + lg * 8;
    const float4 x0 = *reinterpret_cast<const float4*>(&arow[k0]);
    const float4 x1 = *reinterpret_cast<const float4*>(&arow[k0 + 4]);
    const short8 av = cvt8(x0, x1);
#pragma unroll
    for (int fi = 0; fi < 4; ++fi) {
      const short8 bv = *reinterpret_cast<const short8*>(
          &Stb[(size_t)(f0 + fi * 16 + lr) * CN + k0]);
      acc[fi] =
          __builtin_amdgcn_mfma_f32_16x16x32_bf16(av, bv, acc[fi], 0, 0, 0);
    }
  }
#pragma unroll
  for (int fi = 0; fi < 4; ++fi) {
    const int f = f0 + fi * 16 + lr;
    const int n = n0 + lg * 4;
#pragma unroll
    for (int r = 0; r < 4; ++r)
      out[((size_t)b * NADJ + CROP0 + n + r) * F + f] = acc[fi][r];
  }
}

// ---------------------------------------------------------------------------
// Stats: per-(n,f) batch mean / rsqrt(var) over B=64. 512 blocks,
// 4 batch-groups x 16 loads per thread + LDS reduce.
// ---------------------------------------------------------------------------
__global__ __launch_bounds__(256) void stats_kernel(
    const float* __restrict__ out, float* __restrict__ stats) {
  __shared__ float s_l[256], s2_l[256];
  const int jl = threadIdx.x & 63, bg = threadIdx.x >> 6;
  const int j  = blockIdx.x * 64 + jl;  // nl*128+f
  const int nl = j >> 7, f = j & 127;
  const float* p = out + ((size_t)(CROP0 + nl)) * F + f +
                   (size_t)bg * 16 * NADJ * F;
  float s = 0.f, s2 = 0.f;
#pragma unroll 4
  for (int bb = 0; bb < 16; ++bb) {
    const float v = p[(size_t)bb * NADJ * F];
    s += v;
    s2 += v * v;
  }
  s_l[threadIdx.x]  = s;
  s2_l[threadIdx.x] = s2;
  __syncthreads();
  if (threadIdx.x < 64) {
    s  = s_l[jl] + s_l[64 + jl] + s_l[128 + jl] + s_l[192 + jl];
    s2 = s2_l[jl] + s2_l[64 + jl] + s2_l[128 + jl] + s2_l[192 + jl];
    const float mean = s * (1.f / BATCH);
    const float var  = s2 * (1.f / BATCH) - mean * mean;
    stats[j]         = mean;
    stats[32768 + j] = rsqrtf(var + BN_EPS);
  }
}

// ---------------------------------------------------------------------------
// Finalize: full output write. In-crop: normalize in place. Else: beta.
// ---------------------------------------------------------------------------
__global__ __launch_bounds__(256) void finalize_kernel(
    float* __restrict__ out, const float* __restrict__ stats,
    const float* __restrict__ gamma, const float* __restrict__ beta) {
  const size_t i = ((size_t)blockIdx.x * 256 + threadIdx.x) * 4;
  const int nf = (int)(i & (size_t)(NADJ * F - 1));
  const int n  = nf >> 7;
  const float4 bt = *reinterpret_cast<const float4*>(&beta[nf]);
  float4 y;
  if (n >= CROP0 && n < CROP1) {
    const int jj = ((n - CROP0) << 7) | (nf & 127);
    const float4 x  = *reinterpret_cast<const float4*>(&out[i]);
    const float4 mn = *reinterpret_cast<const float4*>(&stats[jj]);
    const float4 rs = *reinterpret_cast<const float4*>(&stats[32768 + jj]);
    const float4 gm = *reinterpret_cast<const float4*>(&gamma[nf]);
    y.x = (x.x - mn.x) * rs.x * gm.x + bt.x;
    y.y = (x.y - mn.y) * rs.y * gm.y + bt.y;
    y.z = (x.z - mn.z) * rs.z * gm.z + bt.z;
    y.w = (x.w - mn.w) * rs.w * gm.w + bt.w;
  } else {
    y = bt;
  }
  *reinterpret_cast<float4*>(&out[i]) = y;
}

extern "C" void kernel_launch(void* const* d_in, const int* in_sizes, int n_in,
                              void* d_out, int out_size, void* d_ws,
                              size_t ws_size, hipStream_t stream) {
  const float* input = (const float*)d_in[0];
  const float* adj   = (const float*)d_in[1];
  const float* W     = (const float*)d_in[2];
  const float* gamma = (const float*)d_in[3];
  const float* beta  = (const float*)d_in[4];
  float* out = (float*)d_out;

  ushort* Wt    = (ushort*)d_ws;                              // 32 KB
  ushort* St    = (ushort*)((char*)d_ws + 64 * 1024);         // 4 MB
  float*  stats = (float*)((char*)d_ws + 64 * 1024 + 4 * 1024 * 1024);

  wprep<<<128, 128, 0, stream>>>(W, Wt);
  support_k<<<512, 256, 0, stream>>>(input, Wt, St);
  aggregate_k<<<512, 256, 0, stream>>>(adj, St, out);
  stats_kernel<<<512, 256, 0, stream>>>(out, stats);
  finalize_kernel<<<4096, 256, 0, stream>>>(out, stats, gamma, beta);
}

// Round 5
// 33.151 us; speedup vs baseline: 1.3316x; 1.3316x over previous
//
#include <hip/hip_runtime.h>
#include <hip/hip_bf16.h>

#define BATCH 64
#define NADJ  512
#define F     128
#define CROP0 128
#define CROP1 384
#define CN    256
#define BN_EPS 1e-5f

typedef __attribute__((ext_vector_type(8))) short short8;
typedef __attribute__((ext_vector_type(4))) float f32x4;

__device__ __forceinline__ ushort f2bf(float x) {
  __hip_bfloat16 h = __float2bfloat16(x);  // RNE
  return *reinterpret_cast<ushort*>(&h);
}

// ---------------------------------------------------------------------------
// K1: St[b][f][m] = bf16( (input_crop @ W)^T ), m-tile 32 per block.
// No W-prep pass: each wave loads its 64-f half of W straight from fp32
// global (64B-coalesced across 16 lanes), converts in-register.
// ---------------------------------------------------------------------------
__global__ __launch_bounds__(256) void support_k(
    const float* __restrict__ input, const float* __restrict__ W,
    ushort* __restrict__ St) {
  const int b  = blockIdx.x >> 3;
  const int m0 = (blockIdx.x & 7) * 32;
  __shared__ ushort ain[32][136];  // 272B row stride = 17x16B, conflict-free
  const int tid = threadIdx.x;
  const float* inb = input + ((size_t)b * NADJ + CROP0 + m0) * F;

  for (int idx = tid; idx < 32 * 32; idx += 256) {
    const int ml = idx >> 5, c4 = (idx & 31) * 4;
    const float4 v = *reinterpret_cast<const float4*>(&inb[(size_t)ml * F + c4]);
    *reinterpret_cast<ushort4*>(&ain[ml][c4]) =
        make_ushort4(f2bf(v.x), f2bf(v.y), f2bf(v.z), f2bf(v.w));
  }
  __syncthreads();

  const int l = tid & 63, w = tid >> 6;
  const int lr = l & 15, lg = l >> 4;
  const int msub = (w & 1) * 16;
  const int f0   = (w >> 1) * 64;
  f32x4 acc[4] = {};

#pragma unroll
  for (int ks = 0; ks < 4; ++ks) {
    const int k0 = ks * 32 + lg * 8;
    const short8 av = *reinterpret_cast<const short8*>(&ain[msub + lr][k0]);
#pragma unroll
    for (int fi = 0; fi < 4; ++fi) {
      const float* wp = &W[(size_t)k0 * F + f0 + fi * 16 + lr];
      short8 bv;
#pragma unroll
      for (int j = 0; j < 8; ++j) bv[j] = (short)f2bf(wp[(size_t)j * F]);
      acc[fi] =
          __builtin_amdgcn_mfma_f32_16x16x32_bf16(av, bv, acc[fi], 0, 0, 0);
    }
  }
  // D: col(f)=lane&15, row(m)=4*(lane>>4)+reg
#pragma unroll
  for (int fi = 0; fi < 4; ++fi) {
    const int f = f0 + fi * 16 + lr;
    *reinterpret_cast<ushort4*>(
        &St[((size_t)b * F + f) * CN + m0 + msub + lg * 4]) =
        make_ushort4(f2bf(acc[fi][0]), f2bf(acc[fi][1]), f2bf(acc[fi][2]),
                     f2bf(acc[fi][3]));
  }
}

// ---------------------------------------------------------------------------
// K2: out_crop[b][n][f] = adj_crop[b][n][:] @ S[b][:][f], n-tile 32 per block.
// adj tile staged in LDS; St B-frags straight from L2 (16B/lane, full lines).
// ---------------------------------------------------------------------------
__global__ __launch_bounds__(256) void aggregate_k(
    const float* __restrict__ adj, const ushort* __restrict__ St,
    float* __restrict__ out) {
  const int b  = blockIdx.x >> 3;
  const int n0 = (blockIdx.x & 7) * 32;
  __shared__ ushort adt[32][264];  // 528B row stride = 33x16B
  const int tid = threadIdx.x;
  const float* adjb = adj + ((size_t)b * NADJ + CROP0 + n0) * NADJ + CROP0;

  for (int idx = tid; idx < 32 * 64; idx += 256) {
    const int nl = idx >> 6, c4 = (idx & 63) * 4;
    const float4 v =
        *reinterpret_cast<const float4*>(&adjb[(size_t)nl * NADJ + c4]);
    *reinterpret_cast<ushort4*>(&adt[nl][c4]) =
        make_ushort4(f2bf(v.x), f2bf(v.y), f2bf(v.z), f2bf(v.w));
  }
  __syncthreads();

  const int l = tid & 63, w = tid >> 6;
  const int lr = l & 15, lg = l >> 4;
  const int nsub = (w & 1) * 16;
  const int f0   = (w >> 1) * 64;
  const ushort* Stb = St + (size_t)b * F * CN;
  f32x4 acc[4] = {};

#pragma unroll 4
  for (int ks = 0; ks < 8; ++ks) {
    const int k0 = ks * 32 + lg * 8;
    const short8 av = *reinterpret_cast<const short8*>(&adt[nsub + lr][k0]);
#pragma unroll
    for (int fi = 0; fi < 4; ++fi) {
      const short8 bv = *reinterpret_cast<const short8*>(
          &Stb[(size_t)(f0 + fi * 16 + lr) * CN + k0]);
      acc[fi] =
          __builtin_amdgcn_mfma_f32_16x16x32_bf16(av, bv, acc[fi], 0, 0, 0);
    }
  }
#pragma unroll
  for (int fi = 0; fi < 4; ++fi) {
    const int f = f0 + fi * 16 + lr;
    const int n = n0 + nsub + lg * 4;
#pragma unroll
    for (int r = 0; r < 4; ++r)
      out[((size_t)b * NADJ + CROP0 + n + r) * F + f] = acc[fi][r];
  }
}

// ---------------------------------------------------------------------------
// K3: fused BN stats + normalize + beta-fill.
// Each thread: 16 batch values in regs -> block reduce -> normalize from regs
// (no re-read). Plus grid-strided beta write of all non-crop rows.
// ---------------------------------------------------------------------------
__global__ __launch_bounds__(256) void bn_fused(
    float* __restrict__ out, const float* __restrict__ gamma,
    const float* __restrict__ beta) {
  __shared__ float s_l[256], s2_l[256], m_l[64], r_l[64];
  const int tid = threadIdx.x;
  const int jl = tid & 63, bg = tid >> 6;
  const int j  = blockIdx.x * 64 + jl;  // 0..32767 = nl*128+f
  const int nl = j >> 7, f = j & 127;
  const int nf = (CROP0 + nl) * F + f;
  float* p = out + (size_t)nf + (size_t)bg * 16 * NADJ * F;

  float x[16];
  float s = 0.f, s2 = 0.f;
#pragma unroll
  for (int bb = 0; bb < 16; ++bb) {
    x[bb] = p[(size_t)bb * NADJ * F];
    s += x[bb];
    s2 += x[bb] * x[bb];
  }
  s_l[tid]  = s;
  s2_l[tid] = s2;
  __syncthreads();
  if (tid < 64) {
    s  = s_l[jl] + s_l[64 + jl] + s_l[128 + jl] + s_l[192 + jl];
    s2 = s2_l[jl] + s2_l[64 + jl] + s2_l[128 + jl] + s2_l[192 + jl];
    const float mean = s * (1.f / BATCH);
    const float var  = s2 * (1.f / BATCH) - mean * mean;
    m_l[jl] = mean;
    r_l[jl] = rsqrtf(var + BN_EPS);
  }
  __syncthreads();
  const float mean = m_l[jl];
  const float a    = r_l[jl] * gamma[nf];
  const float c    = beta[nf] - mean * a;
#pragma unroll
  for (int bb = 0; bb < 16; ++bb)
    p[(size_t)bb * NADJ * F] = x[bb] * a + c;  // coalesced 256B per wave-store

  // beta-fill the non-crop rows: 64b x 256 rows x 128f = 2M floats
  const int gid0 = blockIdx.x * 256 + tid;
#pragma unroll
  for (int q = 0; q < 4; ++q) {
    const int gid = gid0 + q * 131072;
    const int c4  = (gid & 31) * 4;
    const int rr  = (gid >> 5) & 255;
    const int bb  = gid >> 13;
    const int n   = rr < 128 ? rr : rr + 256;
    const float4 bv = *reinterpret_cast<const float4*>(&beta[(size_t)n * F + c4]);
    *reinterpret_cast<float4*>(&out[((size_t)bb * NADJ + n) * F + c4]) = bv;
  }
}

extern "C" void kernel_launch(void* const* d_in, const int* in_sizes, int n_in,
                              void* d_out, int out_size, void* d_ws,
                              size_t ws_size, hipStream_t stream) {
  const float* input = (const float*)d_in[0];
  const float* adj   = (const float*)d_in[1];
  const float* W     = (const float*)d_in[2];
  const float* gamma = (const float*)d_in[3];
  const float* beta  = (const float*)d_in[4];
  float* out = (float*)d_out;

  ushort* St = (ushort*)d_ws;  // 64*128*256 bf16 = 4 MB

  support_k<<<512, 256, 0, stream>>>(input, W, St);
  aggregate_k<<<512, 256, 0, stream>>>(adj, St, out);
  bn_fused<<<512, 256, 0, stream>>>(out, gamma, beta);
}